// Round 6
// baseline (157.472 us; speedup 1.0000x reference)
//
#include <hip/hip_runtime.h>
#include <hip/hip_bf16.h>

#define NROWS 8192
#define DDIM  256
#define BM 128
#define BN 128

typedef __attribute__((ext_vector_type(4))) float f32x4;
typedef __attribute__((ext_vector_type(8))) short bf16x8;
typedef __attribute__((ext_vector_type(4))) short short4v;

__device__ inline short f2bf(float f) {
    union { float f; unsigned u; } c; c.f = f;
    unsigned u = c.u;
    u += 0x7fffu + ((u >> 16) & 1u);   // round-to-nearest-even
    return (short)(u >> 16);
}

// ---------------- pre-pass: f32 -> bf16 convert + row norms -----------------
__global__ __launch_bounds__(256) void convert_norms_kernel(
    const float* __restrict__ x, const float* __restrict__ y,
    short* __restrict__ xb, short* __restrict__ yb,
    float* __restrict__ xsq, float* __restrict__ ysq) {
    int row  = blockIdx.x * 4 + (threadIdx.x >> 6);
    int lane = threadIdx.x & 63;
    const float* src; short* dstb; float* dstn; int r;
    if (row < NROWS) { r = row;        src = x + (size_t)r * DDIM; dstb = xb + (size_t)r * DDIM; dstn = xsq; }
    else             { r = row - NROWS; src = y + (size_t)r * DDIM; dstb = yb + (size_t)r * DDIM; dstn = ysq; }
    f32x4 v = __builtin_nontemporal_load(&((const f32x4*)src)[lane]);  // read-once
    short4v o;
    #pragma unroll
    for (int j = 0; j < 4; ++j) o[j] = f2bf(v[j]);
    ((short4v*)dstb)[lane] = o;                     // re-read by GEMM: keep cached
    float s = v[0]*v[0] + v[1]*v[1] + v[2]*v[2] + v[3]*v[3];
    #pragma unroll
    for (int off = 32; off > 0; off >>= 1) s += __shfl_xor(s, off, 64);
    if (lane == 0) dstn[r] = s;
}

// ------------- main GEMM: NO LDS, fragments direct from L2, no barriers ----
__device__ __forceinline__ void load_frags(const char* const* aP, const char* const* bP,
                                           int off, bf16x8* a, bf16x8* b) {
    #pragma unroll
    for (int m = 0; m < 4; ++m) a[m] = *(const bf16x8*)(aP[m] + off);
    #pragma unroll
    for (int n = 0; n < 4; ++n) b[n] = *(const bf16x8*)(bP[n] + off);
}

__device__ __forceinline__ void do_mfma(const bf16x8* a, const bf16x8* b, f32x4 acc[4][4]) {
    #pragma unroll
    for (int m = 0; m < 4; ++m)
        #pragma unroll
        for (int n = 0; n < 4; ++n)
            acc[m][n] = __builtin_amdgcn_mfma_f32_16x16x32_bf16(
                b[n], a[m], acc[m][n], 0, 0, 0);   // operand-swapped (R5-verified)
}

__global__ __launch_bounds__(256) void rbf_gemm_bf16_kernel(
    const char* __restrict__ Xb, const char* __restrict__ Yb,
    const float* __restrict__ xsq, const float* __restrict__ ysq,
    float* __restrict__ out) {
    const int tid  = threadIdx.x;
    const int lane = tid & 63;
    const int wid  = tid >> 6;

    // T1 XCD-bijective swizzle: 4096 blocks = 8 XCDs x (32 by x 16 bx).
    // Per-XCD working set: 2 MB X-panel + 1 MB Y-panel bf16 -> L2-resident.
    const int bid = blockIdx.x;
    const int xcd = bid & 7;
    const int c   = bid >> 3;
    const int by  = (xcd >> 2) * 32 + (c >> 4);
    const int bx  = (xcd & 3)  * 16 + (c & 15);
    const int brow = by * BM;
    const int bcol = bx * BN;
    const int wr = (wid >> 1) * 64;
    const int wc = (wid & 1) * 64;

    // Per-lane fragment base pointers. For MFMA a/b frag: row = sub + (lane&15),
    // k-bytes (lane>>4)*16 within each 64 B k-step. Wave reads 16 rows x 64 B
    // contiguous per instruction (L2-friendly 64-B requests).
    const char* aP[4]; const char* bP[4];
    #pragma unroll
    for (int m = 0; m < 4; ++m)
        aP[m] = Xb + (size_t)(brow + wr + m * 16 + (lane & 15)) * 512 + ((lane >> 4) << 4);
    #pragma unroll
    for (int n = 0; n < 4; ++n)
        bP[n] = Yb + (size_t)(bcol + wc + n * 16 + (lane & 15)) * 512 + ((lane >> 4) << 4);

    f32x4 acc[4][4] = {};
    bf16x8 aE[4], bE[4], aO[4], bO[4];   // even/odd named sets (no runtime idx)

    load_frags(aP, bP, 0, aE, bE);
    #pragma unroll
    for (int ks = 0; ks < 8; ks += 2) {
        if (ks + 1 < 8) load_frags(aP, bP, (ks + 1) * 64, aO, bO);
        do_mfma(aE, bE, acc);
        if (ks + 2 < 8) load_frags(aP, bP, (ks + 2) * 64, aE, bE);
        if (ks + 1 < 8) do_mfma(aO, bO, acc);
    }

    // Epilogue (R5-verified swapped layout): D col(lane&15) = X-row,
    // D rows = 4 consecutive Y-cols -> dwordx4 stores, 64 B/row segments.
    #pragma unroll
    for (int m = 0; m < 4; ++m) {
        const int R  = brow + wr + m * 16 + (lane & 15);
        const float xsv = xsq[R];
        #pragma unroll
        for (int n = 0; n < 4; ++n) {
            const int C = bcol + wc + n * 16 + ((lane >> 4) << 2);
            const f32x4 ysv = *(const f32x4*)&ysq[C];
            f32x4 v;
            #pragma unroll
            for (int j = 0; j < 4; ++j)
                v[j] = __expf(2.0f * acc[m][n][j] - xsv - ysv[j]);
            *(f32x4*)&out[(size_t)R * NROWS + C] = v;
        }
    }
}

// ---------------- fallback (small ws): f32 reg-staging GEMM -----------------
__global__ __launch_bounds__(256) void row_norms_kernel(
    const float* __restrict__ x, const float* __restrict__ y,
    float* __restrict__ sq) {
    int row  = blockIdx.x * 4 + (threadIdx.x >> 6);
    int lane = threadIdx.x & 63;
    const float* src = (row < NROWS) ? (x + (size_t)row * DDIM)
                                     : (y + (size_t)(row - NROWS) * DDIM);
    f32x4 v = ((const f32x4*)src)[lane];
    float s = v[0]*v[0] + v[1]*v[1] + v[2]*v[2] + v[3]*v[3];
    #pragma unroll
    for (int off = 32; off > 0; off >>= 1) s += __shfl_xor(s, off, 64);
    if (lane == 0) sq[row] = s;
}

__global__ __launch_bounds__(256) void rbf_gemm_f32_kernel(
    const float* __restrict__ X, const float* __restrict__ Y,
    const float* __restrict__ xsq, const float* __restrict__ ysq,
    float* __restrict__ out) {
    __shared__ char lds[2 * BM * 64 * 2];
    char* As = lds;
    char* Bs = lds + BM * 64 * 2;
    const int tid  = threadIdx.x;
    const int lane = tid & 63;
    const int wid  = tid >> 6;
    const int brow = blockIdx.y * BM;
    const int bcol = blockIdx.x * BN;
    const int wr = (wid >> 1) * 64;
    const int wc = (wid & 1) * 64;
    const int srow  = tid >> 1;
    const int shalf = tid & 1;
    const float* aptr = X + (size_t)(brow + srow) * DDIM + shalf * 32;
    const float* bptr = Y + (size_t)(bcol + srow) * DDIM + shalf * 32;
    const int swz = (srow & 7) << 4;
    f32x4 acc[4][4] = {};
    for (int ks = 0; ks < DDIM / 64; ++ks) {
        __syncthreads();
        #pragma unroll
        for (int i = 0; i < 4; ++i) {
            f32x4 a0 = ((const f32x4*)(aptr + ks * 64))[2*i];
            f32x4 a1 = ((const f32x4*)(aptr + ks * 64))[2*i + 1];
            f32x4 b0 = ((const f32x4*)(bptr + ks * 64))[2*i];
            f32x4 b1 = ((const f32x4*)(bptr + ks * 64))[2*i + 1];
            bf16x8 av, bv;
            #pragma unroll
            for (int j = 0; j < 4; ++j) {
                av[j]   = f2bf(a0[j]);  av[4+j] = f2bf(a1[j]);
                bv[j]   = f2bf(b0[j]);  bv[4+j] = f2bf(b1[j]);
            }
            const int cb = shalf * 64 + i * 16;
            *(bf16x8*)(As + srow * 128 + (cb ^ swz)) = av;
            *(bf16x8*)(Bs + srow * 128 + (cb ^ swz)) = bv;
        }
        __syncthreads();
        #pragma unroll
        for (int kk = 0; kk < 2; ++kk) {
            const int kb = kk * 64 + ((lane >> 4) << 4);
            bf16x8 af[4], bf[4];
            #pragma unroll
            for (int m = 0; m < 4; ++m) {
                const int r = wr + m * 16 + (lane & 15);
                af[m] = *(const bf16x8*)(As + r * 128 + (kb ^ ((r & 7) << 4)));
            }
            #pragma unroll
            for (int n = 0; n < 4; ++n) {
                const int cc = wc + n * 16 + (lane & 15);
                bf[n] = *(const bf16x8*)(Bs + cc * 128 + (kb ^ ((cc & 7) << 4)));
            }
            #pragma unroll
            for (int m = 0; m < 4; ++m)
                #pragma unroll
                for (int n = 0; n < 4; ++n)
                    acc[m][n] = __builtin_amdgcn_mfma_f32_16x16x32_bf16(
                        af[m], bf[n], acc[m][n], 0, 0, 0);
        }
    }
    const int r0 = brow + wr + ((lane >> 4) << 2);
    const int c0 = bcol + wc + (lane & 15);
    float xs[4][4];
    #pragma unroll
    for (int m = 0; m < 4; ++m)
        #pragma unroll
        for (int j = 0; j < 4; ++j)
            xs[m][j] = xsq[r0 + m * 16 + j];
    #pragma unroll
    for (int n = 0; n < 4; ++n) {
        const float ys = ysq[c0 + n * 16];
        #pragma unroll
        for (int m = 0; m < 4; ++m) {
            #pragma unroll
            for (int j = 0; j < 4; ++j) {
                const int row = r0 + m * 16 + j;
                const float v = __expf(2.0f * acc[m][n][j] - xs[m][j] - ys);
                out[(size_t)row * NROWS + c0 + n * 16] = v;
            }
        }
    }
}

extern "C" void kernel_launch(void* const* d_in, const int* in_sizes, int n_in,
                              void* d_out, int out_size, void* d_ws, size_t ws_size,
                              hipStream_t stream) {
    const float* x = (const float*)d_in[0];
    const float* y = (const float*)d_in[1];
    float* out = (float*)d_out;

    const size_t xb_bytes = (size_t)NROWS * DDIM * 2;         // 4 MB
    const size_t needed   = 2 * xb_bytes + 2 * NROWS * 4;     // + norms

    if (ws_size >= needed) {
        char*  ws  = (char*)d_ws;
        short* xb  = (short*)ws;
        short* yb  = (short*)(ws + xb_bytes);
        float* xsq = (float*)(ws + 2 * xb_bytes);
        float* ysq = xsq + NROWS;
        convert_norms_kernel<<<dim3(2 * NROWS / 4), dim3(256), 0, stream>>>(
            x, y, xb, yb, xsq, ysq);
        rbf_gemm_bf16_kernel<<<dim3(4096), dim3(256), 0, stream>>>(
            (const char*)xb, (const char*)yb, xsq, ysq, out);
    } else {
        float* sq = (float*)d_ws;
        row_norms_kernel<<<dim3(2 * NROWS / 4), dim3(256), 0, stream>>>(x, y, sq);
        rbf_gemm_f32_kernel<<<dim3(NROWS / BN, NROWS / BM), dim3(256), 0, stream>>>(
            x, y, sq, sq + NROWS, out);
    }
}

// Round 7
// 82.081 us; speedup vs baseline: 1.9185x; 1.9185x over previous
//
#include <hip/hip_runtime.h>
#include <hip/hip_bf16.h>

#define NROWS 8192
#define DDIM  256
#define BM 128
#define BN 128
#define BK 32   // per K-step; A|B interleaved 128B lines -> 16 KB per buffer

typedef __attribute__((ext_vector_type(4))) float f32x4;
typedef __attribute__((ext_vector_type(8))) short bf16x8;
typedef __attribute__((ext_vector_type(4))) short short4v;

__device__ inline short f2bf(float f) {
    union { float f; unsigned u; } c; c.f = f;
    unsigned u = c.u;
    u += 0x7fffu + ((u >> 16) & 1u);   // round-to-nearest-even
    return (short)(u >> 16);
}

// ---------------- pre-pass: f32 -> bf16 convert + row norms -----------------
__global__ __launch_bounds__(256) void convert_norms_kernel(
    const float* __restrict__ x, const float* __restrict__ y,
    short* __restrict__ xb, short* __restrict__ yb,
    float* __restrict__ xsq, float* __restrict__ ysq) {
    int row  = blockIdx.x * 4 + (threadIdx.x >> 6);
    int lane = threadIdx.x & 63;
    const float* src; short* dstb; float* dstn; int r;
    if (row < NROWS) { r = row;        src = x + (size_t)r * DDIM; dstb = xb + (size_t)r * DDIM; dstn = xsq; }
    else             { r = row - NROWS; src = y + (size_t)r * DDIM; dstb = yb + (size_t)r * DDIM; dstn = ysq; }
    f32x4 v = __builtin_nontemporal_load(&((const f32x4*)src)[lane]);  // read-once
    short4v o;
    #pragma unroll
    for (int j = 0; j < 4; ++j) o[j] = f2bf(v[j]);
    ((short4v*)dstb)[lane] = o;                     // re-read by GEMM: keep cached
    float s = v[0]*v[0] + v[1]*v[1] + v[2]*v[2] + v[3]*v[3];
    #pragma unroll
    for (int off = 32; off > 0; off >>= 1) s += __shfl_xor(s, off, 64);
    if (lane == 0) dstn[r] = s;
}

// ---- main GEMM: 2-phase double-buffered staging with counted vmcnt (T3/T4) -
__global__ __launch_bounds__(256) void rbf_gemm_bf16_kernel(
    const char* __restrict__ Xb, const char* __restrict__ Yb,
    const float* __restrict__ xsq, const float* __restrict__ ysq,
    float* __restrict__ out) {
    // Two 16 KB buffers. Each: 128 lines x 128 B, line r = [A row r 64B | B row r 64B],
    // XOR-swizzled within the line by ((r&7)<<4). (format verified in R5)
    __shared__ char lds[2][BM * 128];

    const int tid  = threadIdx.x;
    const int lane = tid & 63;
    const int wid  = tid >> 6;

    // T1 XCD-bijective swizzle: 4096 blocks = 8 XCDs x (32 by x 16 bx).
    const int bid = blockIdx.x;
    const int xcd = bid & 7;
    const int c   = bid >> 3;
    const int by  = (xcd >> 2) * 32 + (c >> 4);
    const int bx  = (xcd & 3)  * 16 + (c & 15);
    const int brow = by * BM;
    const int bcol = bx * BN;
    const int wr = (wid >> 1) * 64;
    const int wc = (wid & 1) * 64;

    // Pre-swizzled global sources (rule #21; mapping verified in R5).
    const char* src[4];
    #pragma unroll
    for (int i = 0; i < 4; ++i) {
        const int q    = i * 4096 + tid * 16;
        const int line = q >> 7;
        const int scol = (q & 127) ^ ((line & 7) << 4);
        src[i] = (scol < 64)
            ? Xb + (size_t)(brow + line) * 512 + scol
            : Yb + (size_t)(bcol + line) * 512 + (scol - 64);
    }

    const int swz = (lane & 7) << 4;
    const int kq  = (lane >> 4) << 4;

    f32x4 acc[4][4] = {};

    #define STAGE(buf, ks)                                                         \
        _Pragma("unroll")                                                          \
        for (int i = 0; i < 4; ++i)                                                \
            __builtin_amdgcn_global_load_lds(                                      \
                (const __attribute__((address_space(1))) void*)(src[i] + (ks) * 64), \
                (__attribute__((address_space(3))) void*)((buf) + i * 4096 + wid * 1024), \
                16, 0, 0);

    // prologue: stage tile 0, full wait
    STAGE(&lds[0][0], 0)
    asm volatile("s_waitcnt vmcnt(0)" ::: "memory");
    __builtin_amdgcn_s_barrier();

    #pragma unroll
    for (int ks = 0; ks < 8; ++ks) {
        char* cur = &lds[ks & 1][0];
        char* nxt = &lds[(ks & 1) ^ 1][0];
        if (ks < 7) STAGE(nxt, ks + 1)     // issue-early: overlaps compute below

        bf16x8 af[4], bf[4];
        #pragma unroll
        for (int m = 0; m < 4; ++m) {
            const int r = wr + m * 16 + (lane & 15);
            af[m] = *(const bf16x8*)(cur + r * 128 + (kq ^ swz));
        }
        #pragma unroll
        for (int n = 0; n < 4; ++n) {
            const int r = wc + n * 16 + (lane & 15);
            bf[n] = *(const bf16x8*)(cur + r * 128 + ((64 + kq) ^ swz));
        }
        #pragma unroll
        for (int m = 0; m < 4; ++m)
            #pragma unroll
            for (int n = 0; n < 4; ++n)
                acc[m][n] = __builtin_amdgcn_mfma_f32_16x16x32_bf16(
                    bf[n], af[m], acc[m][n], 0, 0, 0);   // swapped (R5/R6-verified)

        // wait only for the next-tile stage (counted at end of compute), then
        // barrier. All reads of `nxt`'s previous contents finished before the
        // PREVIOUS barrier, so the in-flight writes are race-free.
        asm volatile("s_waitcnt vmcnt(0)" ::: "memory");
        __builtin_amdgcn_s_barrier();
    }
    #undef STAGE

    // Epilogue (swapped layout, verified R5/R6): D col(lane&15) = X-row,
    // 4 regs = 4 consecutive Y-cols -> dwordx4 stores.
    #pragma unroll
    for (int m = 0; m < 4; ++m) {
        const int R  = brow + wr + m * 16 + (lane & 15);
        const float xsv = xsq[R];
        #pragma unroll
        for (int n = 0; n < 4; ++n) {
            const int C = bcol + wc + n * 16 + ((lane >> 4) << 2);
            const f32x4 ysv = *(const f32x4*)&ysq[C];
            f32x4 v;
            #pragma unroll
            for (int j = 0; j < 4; ++j)
                v[j] = __expf(2.0f * acc[m][n][j] - xsv - ysv[j]);
            *(f32x4*)&out[(size_t)R * NROWS + C] = v;
        }
    }
}

// ---------------- fallback (small ws): f32 reg-staging GEMM -----------------
__global__ __launch_bounds__(256) void row_norms_kernel(
    const float* __restrict__ x, const float* __restrict__ y,
    float* __restrict__ sq) {
    int row  = blockIdx.x * 4 + (threadIdx.x >> 6);
    int lane = threadIdx.x & 63;
    const float* src = (row < NROWS) ? (x + (size_t)row * DDIM)
                                     : (y + (size_t)(row - NROWS) * DDIM);
    f32x4 v = ((const f32x4*)src)[lane];
    float s = v[0]*v[0] + v[1]*v[1] + v[2]*v[2] + v[3]*v[3];
    #pragma unroll
    for (int off = 32; off > 0; off >>= 1) s += __shfl_xor(s, off, 64);
    if (lane == 0) sq[row] = s;
}

__global__ __launch_bounds__(256) void rbf_gemm_f32_kernel(
    const float* __restrict__ X, const float* __restrict__ Y,
    const float* __restrict__ xsq, const float* __restrict__ ysq,
    float* __restrict__ out) {
    __shared__ char lds[2 * BM * 64 * 2];
    char* As = lds;
    char* Bs = lds + BM * 64 * 2;
    const int tid  = threadIdx.x;
    const int lane = tid & 63;
    const int wid  = tid >> 6;
    const int brow = blockIdx.y * BM;
    const int bcol = blockIdx.x * BN;
    const int wr = (wid >> 1) * 64;
    const int wc = (wid & 1) * 64;
    const int srow  = tid >> 1;
    const int shalf = tid & 1;
    const float* aptr = X + (size_t)(brow + srow) * DDIM + shalf * 32;
    const float* bptr = Y + (size_t)(bcol + srow) * DDIM + shalf * 32;
    const int swz = (srow & 7) << 4;
    f32x4 acc[4][4] = {};
    for (int ks = 0; ks < DDIM / 64; ++ks) {
        __syncthreads();
        #pragma unroll
        for (int i = 0; i < 4; ++i) {
            f32x4 a0 = ((const f32x4*)(aptr + ks * 64))[2*i];
            f32x4 a1 = ((const f32x4*)(aptr + ks * 64))[2*i + 1];
            f32x4 b0 = ((const f32x4*)(bptr + ks * 64))[2*i];
            f32x4 b1 = ((const f32x4*)(bptr + ks * 64))[2*i + 1];
            bf16x8 av, bv;
            #pragma unroll
            for (int j = 0; j < 4; ++j) {
                av[j]   = f2bf(a0[j]);  av[4+j] = f2bf(a1[j]);
                bv[j]   = f2bf(b0[j]);  bv[4+j] = f2bf(b1[j]);
            }
            const int cb = shalf * 64 + i * 16;
            *(bf16x8*)(As + srow * 128 + (cb ^ swz)) = av;
            *(bf16x8*)(Bs + srow * 128 + (cb ^ swz)) = bv;
        }
        __syncthreads();
        #pragma unroll
        for (int kk = 0; kk < 2; ++kk) {
            const int kb = kk * 64 + ((lane >> 4) << 4);
            bf16x8 af[4], bf[4];
            #pragma unroll
            for (int m = 0; m < 4; ++m) {
                const int r = wr + m * 16 + (lane & 15);
                af[m] = *(const bf16x8*)(As + r * 128 + (kb ^ ((r & 7) << 4)));
            }
            #pragma unroll
            for (int n = 0; n < 4; ++n) {
                const int cc = wc + n * 16 + (lane & 15);
                bf[n] = *(const bf16x8*)(Bs + cc * 128 + (kb ^ ((cc & 7) << 4)));
            }
            #pragma unroll
            for (int m = 0; m < 4; ++m)
                #pragma unroll
                for (int n = 0; n < 4; ++n)
                    acc[m][n] = __builtin_amdgcn_mfma_f32_16x16x32_bf16(
                        af[m], bf[n], acc[m][n], 0, 0, 0);
        }
    }
    const int r0 = brow + wr + ((lane >> 4) << 2);
    const int c0 = bcol + wc + (lane & 15);
    float xs[4][4];
    #pragma unroll
    for (int m = 0; m < 4; ++m)
        #pragma unroll
        for (int j = 0; j < 4; ++j)
            xs[m][j] = xsq[r0 + m * 16 + j];
    #pragma unroll
    for (int n = 0; n < 4; ++n) {
        const float ys = ysq[c0 + n * 16];
        #pragma unroll
        for (int m = 0; m < 4; ++m) {
            #pragma unroll
            for (int j = 0; j < 4; ++j) {
                const int row = r0 + m * 16 + j;
                const float v = __expf(2.0f * acc[m][n][j] - xs[m][j] - ys);
                out[(size_t)row * NROWS + c0 + n * 16] = v;
            }
        }
    }
}

extern "C" void kernel_launch(void* const* d_in, const int* in_sizes, int n_in,
                              void* d_out, int out_size, void* d_ws, size_t ws_size,
                              hipStream_t stream) {
    const float* x = (const float*)d_in[0];
    const float* y = (const float*)d_in[1];
    float* out = (float*)d_out;

    const size_t xb_bytes = (size_t)NROWS * DDIM * 2;         // 4 MB
    const size_t needed   = 2 * xb_bytes + 2 * NROWS * 4;     // + norms

    if (ws_size >= needed) {
        char*  ws  = (char*)d_ws;
        short* xb  = (short*)ws;
        short* yb  = (short*)(ws + xb_bytes);
        float* xsq = (float*)(ws + 2 * xb_bytes);
        float* ysq = xsq + NROWS;
        convert_norms_kernel<<<dim3(2 * NROWS / 4), dim3(256), 0, stream>>>(
            x, y, xb, yb, xsq, ysq);
        rbf_gemm_bf16_kernel<<<dim3(4096), dim3(256), 0, stream>>>(
            (const char*)xb, (const char*)yb, xsq, ysq, out);
    } else {
        float* sq = (float*)d_ws;
        row_norms_kernel<<<dim3(2 * NROWS / 4), dim3(256), 0, stream>>>(x, y, sq);
        rbf_gemm_f32_kernel<<<dim3(NROWS / BN, NROWS / BM), dim3(256), 0, stream>>>(
            x, y, sq, sq + NROWS, out);
    }
}

// Round 8
// 70.251 us; speedup vs baseline: 2.2416x; 1.1684x over previous
//
#include <hip/hip_runtime.h>
#include <hip/hip_bf16.h>

#define NROWS 8192
#define DDIM  256
#define BM 128
#define BN 128
#define BK 64

typedef __attribute__((ext_vector_type(4))) float f32x4;
typedef __attribute__((ext_vector_type(8))) short bf16x8;
typedef __attribute__((ext_vector_type(4))) short short4v;

__device__ inline short f2bf(float f) {
    union { float f; unsigned u; } c; c.f = f;
    unsigned u = c.u;
    u += 0x7fffu + ((u >> 16) & 1u);   // round-to-nearest-even
    return (short)(u >> 16);
}

// ---------------- pre-pass: f32 -> bf16 convert + row norms -----------------
__global__ __launch_bounds__(256) void convert_norms_kernel(
    const float* __restrict__ x, const float* __restrict__ y,
    short* __restrict__ xb, short* __restrict__ yb,
    float* __restrict__ xsq, float* __restrict__ ysq) {
    int row  = blockIdx.x * 4 + (threadIdx.x >> 6);
    int lane = threadIdx.x & 63;
    const float* src; short* dstb; float* dstn; int r;
    if (row < NROWS) { r = row;        src = x + (size_t)r * DDIM; dstb = xb + (size_t)r * DDIM; dstn = xsq; }
    else             { r = row - NROWS; src = y + (size_t)r * DDIM; dstb = yb + (size_t)r * DDIM; dstn = ysq; }
    f32x4 v = __builtin_nontemporal_load(&((const f32x4*)src)[lane]);  // read-once
    short4v o;
    #pragma unroll
    for (int j = 0; j < 4; ++j) o[j] = f2bf(v[j]);
    ((short4v*)dstb)[lane] = o;                     // re-read by GEMM: keep cached
    float s = v[0]*v[0] + v[1]*v[1] + v[2]*v[2] + v[3]*v[3];
    #pragma unroll
    for (int off = 32; off > 0; off >>= 1) s += __shfl_xor(s, off, 64);
    if (lane == 0) dstn[r] = s;
}

// -------- main GEMM: R4 staging/K-loop + LDS-shuffle contiguous epilogue ----
__global__ __launch_bounds__(256) void rbf_gemm_bf16_kernel(
    const char* __restrict__ Xb, const char* __restrict__ Yb,
    const float* __restrict__ xsq, const float* __restrict__ ysq,
    float* __restrict__ out) {
    __shared__ char lds[2 * BM * BK * 2];   // 32 KB: As | Bs; reused by epilogue
    char* As = lds;
    char* Bs = lds + BM * BK * 2;

    const int tid  = threadIdx.x;
    const int lane = tid & 63;
    const int wid  = tid >> 6;

    // T1 XCD-bijective swizzle: 4096 blocks = 8 XCDs x (32 by x 16 bx).
    const int bid = blockIdx.x;
    const int xcd = bid & 7;
    const int c   = bid >> 3;
    const int by  = (xcd >> 2) * 32 + (c >> 4);
    const int bx  = (xcd & 3)  * 16 + (c & 15);
    const int brow = by * BM;
    const int bcol = bx * BN;
    const int wr = (wid >> 1) * 64;
    const int wc = (wid & 1) * 64;

    // Pre-swizzled per-lane global source addresses (rule #21; R2/R4-verified).
    const char* aS[4]; const char* bS[4];
    #pragma unroll
    for (int i = 0; i < 4; ++i) {
        const int q    = i * 4096 + tid * 16;       // linear LDS byte pos
        const int row  = q >> 7;                    // 128 B per tile row
        const int colb = q & 127;
        const int sc   = colb ^ ((row & 7) << 4);   // inverse swizzle (involution)
        aS[i] = Xb + (size_t)(brow + row) * 512 + sc;
        bS[i] = Yb + (size_t)(bcol + row) * 512 + sc;
    }

    f32x4 acc[4][4] = {};

    for (int ks = 0; ks < DDIM / BK; ++ks) {
        #pragma unroll
        for (int i = 0; i < 4; ++i) {
            __builtin_amdgcn_global_load_lds(
                (const __attribute__((address_space(1))) void*)(aS[i] + ks * 128),
                (__attribute__((address_space(3))) void*)(As + i * 4096 + wid * 1024),
                16, 0, 0);
            __builtin_amdgcn_global_load_lds(
                (const __attribute__((address_space(1))) void*)(bS[i] + ks * 128),
                (__attribute__((address_space(3))) void*)(Bs + i * 4096 + wid * 1024),
                16, 0, 0);
        }
        __syncthreads();

        #pragma unroll
        for (int kk = 0; kk < 2; ++kk) {
            const int kb = kk * 64 + ((lane >> 4) << 4);
            bf16x8 af[4], bf[4];
            #pragma unroll
            for (int m = 0; m < 4; ++m) {
                const int r = wr + m * 16 + (lane & 15);
                af[m] = *(const bf16x8*)(As + r * 128 + (kb ^ ((r & 7) << 4)));
            }
            #pragma unroll
            for (int n = 0; n < 4; ++n) {
                const int cc = wc + n * 16 + (lane & 15);
                bf[n] = *(const bf16x8*)(Bs + cc * 128 + (kb ^ ((cc & 7) << 4)));
            }
            #pragma unroll
            for (int m = 0; m < 4; ++m)
                #pragma unroll
                for (int n = 0; n < 4; ++n)
                    acc[m][n] = __builtin_amdgcn_mfma_f32_16x16x32_bf16(
                        bf[n], af[m], acc[m][n], 0, 0, 0);   // swapped (R5/R6/R7-verified)
        }
        __syncthreads();
    }

    // -------- epilogue: exp + LDS shuffle -> contiguous 512-B row stores ----
    // Swapped-D layout: acc[m][n] reg j -> X-row brow+wr+m*16+(lane&15),
    //                   Y-col bcol+wc+n*16+(lane>>4)*4 + j  (R5-verified).
    // Per m-slice: 32 rows x 128 cols f32 = 16 KB staged in LDS (reuse As|Bs).
    const int rl  = ((wid >> 1) << 4) + (lane & 15);        // row_local [0,32)
    const int rgl = rl + ((rl & 16) ? 48 : 0);              // tile-row offset (pre-m)
    f32x4 ys4[4];
    #pragma unroll
    for (int n = 0; n < 4; ++n)
        ys4[n] = *(const f32x4*)&ysq[bcol + wc + n * 16 + ((lane >> 4) << 2)];

    #pragma unroll
    for (int m = 0; m < 4; ++m) {
        const float xsv = xsq[brow + m * 16 + rgl];
        #pragma unroll
        for (int n = 0; n < 4; ++n) {
            f32x4 v;
            #pragma unroll
            for (int j = 0; j < 4; ++j)
                v[j] = __expf(2.0f * acc[m][n][j] - xsv - ys4[n][j]);
            // slot = col_local/4 in [0,32); XOR-swizzled vs row
            const int slot = ((wid & 1) << 4) + (n << 2) + (lane >> 4);
            *(f32x4*)(lds + rl * 512 + ((slot ^ (rl & 7)) << 4)) = v;
        }
        __syncthreads();
        #pragma unroll
        for (int p = 0; p < 4; ++p) {
            const int rr    = (p << 3) + (tid >> 5);        // row_local
            const int slot2 = tid & 31;
            const f32x4 v = *(const f32x4*)(lds + rr * 512 + ((slot2 ^ (rr & 7)) << 4));
            const int growr = brow + (m << 4) + rr + ((rr & 16) ? 48 : 0);
            // 32 consecutive threads -> one contiguous 512-B output row segment
            *(f32x4*)&out[(size_t)growr * NROWS + bcol + (slot2 << 2)] = v;
        }
        __syncthreads();
    }
}

// ---------------- fallback (small ws): f32 reg-staging GEMM -----------------
__global__ __launch_bounds__(256) void row_norms_kernel(
    const float* __restrict__ x, const float* __restrict__ y,
    float* __restrict__ sq) {
    int row  = blockIdx.x * 4 + (threadIdx.x >> 6);
    int lane = threadIdx.x & 63;
    const float* src = (row < NROWS) ? (x + (size_t)row * DDIM)
                                     : (y + (size_t)(row - NROWS) * DDIM);
    f32x4 v = ((const f32x4*)src)[lane];
    float s = v[0]*v[0] + v[1]*v[1] + v[2]*v[2] + v[3]*v[3];
    #pragma unroll
    for (int off = 32; off > 0; off >>= 1) s += __shfl_xor(s, off, 64);
    if (lane == 0) sq[row] = s;
}

__global__ __launch_bounds__(256) void rbf_gemm_f32_kernel(
    const float* __restrict__ X, const float* __restrict__ Y,
    const float* __restrict__ xsq, const float* __restrict__ ysq,
    float* __restrict__ out) {
    __shared__ char lds[2 * BM * 64 * 2];
    char* As = lds;
    char* Bs = lds + BM * 64 * 2;
    const int tid  = threadIdx.x;
    const int lane = tid & 63;
    const int wid  = tid >> 6;
    const int brow = blockIdx.y * BM;
    const int bcol = blockIdx.x * BN;
    const int wr = (wid >> 1) * 64;
    const int wc = (wid & 1) * 64;
    const int srow  = tid >> 1;
    const int shalf = tid & 1;
    const float* aptr = X + (size_t)(brow + srow) * DDIM + shalf * 32;
    const float* bptr = Y + (size_t)(bcol + srow) * DDIM + shalf * 32;
    const int swz = (srow & 7) << 4;
    f32x4 acc[4][4] = {};
    for (int ks = 0; ks < DDIM / 64; ++ks) {
        __syncthreads();
        #pragma unroll
        for (int i = 0; i < 4; ++i) {
            f32x4 a0 = ((const f32x4*)(aptr + ks * 64))[2*i];
            f32x4 a1 = ((const f32x4*)(aptr + ks * 64))[2*i + 1];
            f32x4 b0 = ((const f32x4*)(bptr + ks * 64))[2*i];
            f32x4 b1 = ((const f32x4*)(bptr + ks * 64))[2*i + 1];
            bf16x8 av, bv;
            #pragma unroll
            for (int j = 0; j < 4; ++j) {
                av[j]   = f2bf(a0[j]);  av[4+j] = f2bf(a1[j]);
                bv[j]   = f2bf(b0[j]);  bv[4+j] = f2bf(b1[j]);
            }
            const int cb = shalf * 64 + i * 16;
            *(bf16x8*)(As + srow * 128 + (cb ^ swz)) = av;
            *(bf16x8*)(Bs + srow * 128 + (cb ^ swz)) = bv;
        }
        __syncthreads();
        #pragma unroll
        for (int kk = 0; kk < 2; ++kk) {
            const int kb = kk * 64 + ((lane >> 4) << 4);
            bf16x8 af[4], bf[4];
            #pragma unroll
            for (int m = 0; m < 4; ++m) {
                const int r = wr + m * 16 + (lane & 15);
                af[m] = *(const bf16x8*)(As + r * 128 + (kb ^ ((r & 7) << 4)));
            }
            #pragma unroll
            for (int n = 0; n < 4; ++n) {
                const int cc = wc + n * 16 + (lane & 15);
                bf[n] = *(const bf16x8*)(Bs + cc * 128 + (kb ^ ((cc & 7) << 4)));
            }
            #pragma unroll
            for (int m = 0; m < 4; ++m)
                #pragma unroll
                for (int n = 0; n < 4; ++n)
                    acc[m][n] = __builtin_amdgcn_mfma_f32_16x16x32_bf16(
                        af[m], bf[n], acc[m][n], 0, 0, 0);
        }
    }
    const int r0 = brow + wr + ((lane >> 4) << 2);
    const int c0 = bcol + wc + (lane & 15);
    float xs[4][4];
    #pragma unroll
    for (int m = 0; m < 4; ++m)
        #pragma unroll
        for (int j = 0; j < 4; ++j)
            xs[m][j] = xsq[r0 + m * 16 + j];
    #pragma unroll
    for (int n = 0; n < 4; ++n) {
        const float ys = ysq[c0 + n * 16];
        #pragma unroll
        for (int m = 0; m < 4; ++m) {
            #pragma unroll
            for (int j = 0; j < 4; ++j) {
                const int row = r0 + m * 16 + j;
                const float v = __expf(2.0f * acc[m][n][j] - xs[m][j] - ys);
                out[(size_t)row * NROWS + c0 + n * 16] = v;
            }
        }
    }
}

extern "C" void kernel_launch(void* const* d_in, const int* in_sizes, int n_in,
                              void* d_out, int out_size, void* d_ws, size_t ws_size,
                              hipStream_t stream) {
    const float* x = (const float*)d_in[0];
    const float* y = (const float*)d_in[1];
    float* out = (float*)d_out;

    const size_t xb_bytes = (size_t)NROWS * DDIM * 2;         // 4 MB
    const size_t needed   = 2 * xb_bytes + 2 * NROWS * 4;     // + norms

    if (ws_size >= needed) {
        char*  ws  = (char*)d_ws;
        short* xb  = (short*)ws;
        short* yb  = (short*)(ws + xb_bytes);
        float* xsq = (float*)(ws + 2 * xb_bytes);
        float* ysq = xsq + NROWS;
        convert_norms_kernel<<<dim3(2 * NROWS / 4), dim3(256), 0, stream>>>(
            x, y, xb, yb, xsq, ysq);
        rbf_gemm_bf16_kernel<<<dim3(4096), dim3(256), 0, stream>>>(
            (const char*)xb, (const char*)yb, xsq, ysq, out);
    } else {
        float* sq = (float*)d_ws;
        row_norms_kernel<<<dim3(2 * NROWS / 4), dim3(256), 0, stream>>>(x, y, sq);
        rbf_gemm_f32_kernel<<<dim3(NROWS / BN, NROWS / BM), dim3(256), 0, stream>>>(
            x, y, sq, sq + NROWS, out);
    }
}